// Round 1
// baseline (4818.430 us; speedup 1.0000x reference)
//
#include <hip/hip_runtime.h>
#include <cstdint>

// ---------------- problem constants ----------------
#define DD 8
#define HH 32
#define WW 32
#define NPOS 8192              // 8*32*32
#define XP_SY 34
#define XP_SZ (34*34)          // 1156
#define XP_SC (10*34*34)       // 11560 floats per channel (z padded to 10, y/x to 34)
#define XP_ELEMS (256*XP_SC)   // 2,959,360 floats

typedef float facc_t __attribute__((ext_vector_type(4)));
typedef short bf8_t  __attribute__((ext_vector_type(8)));   // 8 bf16 in 4 VGPRs
typedef unsigned short ub8_t __attribute__((ext_vector_type(8)));

__device__ __forceinline__ unsigned short f2bf(float f) {
    unsigned u = __float_as_uint(f);
    u = (u + 0x7FFFu + ((u >> 16) & 1u)) >> 16;   // RNE
    return (unsigned short)u;
}

// ---------------- pad-copy: X (256,8,32,32) -> Xp (256,10,34,34), zero halo ----------------
__global__ void pad_kernel(const float* __restrict__ X, float* __restrict__ Xp) {
    int t = blockIdx.x * 256 + threadIdx.x;
    if (t >= XP_ELEMS) return;
    int xp = t % 34;
    int r  = t / 34;
    int yp = r % 34;
    r /= 34;
    int zp = r % 10;
    int c  = r / 10;
    float v = 0.f;
    if (zp >= 1 && zp <= 8 && yp >= 1 && yp <= 32 && xp >= 1 && xp <= 32) {
        v = X[((c * 8 + (zp - 1)) * 32 + (yp - 1)) * 32 + (xp - 1)];
    }
    Xp[t] = v;
}

// ---------------- weight transpose: (O,256,27) f32 -> [27][Opad][256] bf16, zero-pad o>=O ----------------
__global__ void wtrans_kernel(const float* __restrict__ w, unsigned short* __restrict__ wt,
                              int O, int Opad) {
    int t = blockIdx.x * 256 + threadIdx.x;
    int total = 27 * Opad * 256;
    if (t >= total) return;
    int c = t & 255;
    int o = (t >> 8) % Opad;
    int k = t / (Opad * 256);
    float v = (o < O) ? w[(o * 256 + c) * 27 + k] : 0.f;
    wt[t] = f2bf(v);
}

// ---------------- unified implicit-GEMM (conv / deformable) ----------------
// out[o][p] = bias[o] + sum_{k<27, c<256} wt[k][o][c] * samp(c, k, p)
// conv mode:   samp = Xp at integer tap shift
// deform mode: samp = trilinear(Xp, tap + offset) * sigmoid-mask (dbuf holds 108 ch: 81 off + 27 mask)
// epi: 0 = bias, 1 = bias+relu, 2 = bias + sigmoid on oc>=81 (offset-conv output)
template<bool IS_CONV>
__global__ __launch_bounds__(256)
void gemm_kernel(const float* __restrict__ Xp,
                 const unsigned short* __restrict__ wt,   // [27][Opad][256] bf16
                 const float* __restrict__ dbuf,          // [108][8192] or null
                 const float* __restrict__ bias,          // [O]
                 float* __restrict__ out,                 // [O][8192]
                 int O, int Opad, int epi) {
    __shared__ unsigned short w_s[128 * 32] __attribute__((aligned(16)));
    __shared__ unsigned short samp_s[64 * 32] __attribute__((aligned(16)));

    const int t    = threadIdx.x;
    const int wave = t >> 6;
    const int lane = t & 63;
    const int q    = lane >> 4;    // 0..3
    const int r    = lane & 15;    // 0..15

    const int pbase = blockIdx.x * 64;
    const int obase = blockIdx.y * 128;

    const int pl = lane;                 // this thread's staging position
    const int p  = pbase + pl;
    const int z = p >> 10, y = (p >> 5) & 31, x = p & 31;

    facc_t acc[2][4];
#pragma unroll
    for (int i = 0; i < 2; ++i)
#pragma unroll
        for (int j = 0; j < 4; ++j) acc[i][j] = (facc_t){0.f, 0.f, 0.f, 0.f};

    for (int k = 0; k < 27; ++k) {
        const int kd = k / 9, kh = (k / 3) % 3, kw = k % 3;

        // ---- per-position corner setup (registers; all 4 waves mirror for their lane's p) ----
        float cw8[8];
        int cbase;
        if (IS_CONV) {
            cbase = (z + kd) * XP_SZ + (y + kh) * XP_SY + (x + kw);
#pragma unroll
            for (int j = 0; j < 8; ++j) cw8[j] = 0.f;   // unused
        } else {
            float od = dbuf[(3 * k + 0) * NPOS + p];
            float oh = dbuf[(3 * k + 1) * NPOS + p];
            float ow = dbuf[(3 * k + 2) * NPOS + p];
            float m  = dbuf[(81 + k) * NPOS + p];
            float cd = (float)(z + kd - 1) + od;
            float ch = (float)(y + kh - 1) + oh;
            float cx = (float)(x + kw - 1) + ow;
            float fdf = floorf(cd), fhf = floorf(ch), fwf = floorf(cx);
            float fd = cd - fdf, fh = ch - fhf, fw = cx - fwf;
            int id = (int)fdf, ih = (int)fhf, iw = (int)fwf;
            float wz0 = 1.f - fd, wz1 = fd;
            if (id < -1 || id > DD - 1) { wz0 = 0.f; wz1 = 0.f; id = 0; }
            float wy0 = 1.f - fh, wy1 = fh;
            if (ih < -1 || ih > HH - 1) { wy0 = 0.f; wy1 = 0.f; ih = 0; }
            float wx0 = 1.f - fw, wx1 = fw;
            if (iw < -1 || iw > WW - 1) { wx0 = 0.f; wx1 = 0.f; iw = 0; }
            wz0 *= m; wz1 *= m;
            float w00 = wz0 * wy0, w01 = wz0 * wy1, w10 = wz1 * wy0, w11 = wz1 * wy1;
            cw8[0] = w00 * wx0; cw8[1] = w00 * wx1;
            cw8[2] = w01 * wx0; cw8[3] = w01 * wx1;
            cw8[4] = w10 * wx0; cw8[5] = w10 * wx1;
            cw8[6] = w11 * wx0; cw8[7] = w11 * wx1;
            cbase = (id + 1) * XP_SZ + (ih + 1) * XP_SY + (iw + 1);
        }

        for (int c0 = 0; c0 < 256; c0 += 32) {
            // ---- stage weight tile: 128 o-rows x 32 c (bf16), 16B chunks ----
            {
                int idx = t;
#pragma unroll
                for (int it = 0; it < 2; ++it) {
                    int row = idx >> 2;
                    int sub = idx & 3;
                    ub8_t v = *(const ub8_t*)&wt[((k * Opad + obase + row) * 256) + c0 + sub * 8];
                    *(ub8_t*)&w_s[row * 32 + sub * 8] = v;
                    idx += 256;
                }
            }
            // ---- stage sampled tile: this thread: 8 channels (c0+wave*8+j) at position pl ----
            {
                const float* Xc = Xp + (c0 + wave * 8) * XP_SC + cbase;
                ub8_t pk;
#pragma unroll
                for (int j = 0; j < 8; ++j) {
                    const float* qp = Xc + j * XP_SC;
                    float v;
                    if (IS_CONV) {
                        v = qp[0];
                    } else {
                        v = cw8[0] * qp[0]              + cw8[1] * qp[1]
                          + cw8[2] * qp[XP_SY]          + cw8[3] * qp[XP_SY + 1]
                          + cw8[4] * qp[XP_SZ]          + cw8[5] * qp[XP_SZ + 1]
                          + cw8[6] * qp[XP_SZ + XP_SY]  + cw8[7] * qp[XP_SZ + XP_SY + 1];
                    }
                    pk[j] = f2bf(v);
                }
                *(ub8_t*)&samp_s[pl * 32 + wave * 8] = pk;
            }
            __syncthreads();
            // ---- MFMA: wave computes o in [obase+wave*32, +32), p in [pbase, +64) ----
            bf8_t a0 = *(const bf8_t*)&w_s[(wave * 32 + r) * 32 + q * 8];
            bf8_t a1 = *(const bf8_t*)&w_s[(wave * 32 + 16 + r) * 32 + q * 8];
#pragma unroll
            for (int ip = 0; ip < 4; ++ip) {
                bf8_t b = *(const bf8_t*)&samp_s[(ip * 16 + r) * 32 + q * 8];
                acc[0][ip] = __builtin_amdgcn_mfma_f32_16x16x32_bf16(a0, b, acc[0][ip], 0, 0, 0);
                acc[1][ip] = __builtin_amdgcn_mfma_f32_16x16x32_bf16(a1, b, acc[1][ip], 0, 0, 0);
            }
            __syncthreads();
        }
    }

    // ---- epilogue: D row = o (quad*4+reg), col = p (lane&15) per verified C/D map ----
#pragma unroll
    for (int io = 0; io < 2; ++io) {
#pragma unroll
        for (int reg = 0; reg < 4; ++reg) {
            int o = obase + wave * 32 + io * 16 + q * 4 + reg;
            if (o < O) {
                float bv = bias[o];
#pragma unroll
                for (int ip = 0; ip < 4; ++ip) {
                    int pp = pbase + ip * 16 + r;
                    float v = acc[io][ip][reg] + bv;
                    if (epi == 1) v = fmaxf(v, 0.f);
                    else if (epi == 2 && o >= 81) v = 1.f / (1.f + __expf(-v));
                    out[o * NPOS + pp] = v;
                }
            }
        }
    }
}

// ---------------- host orchestration ----------------
extern "C" void kernel_launch(void* const* d_in, const int* in_sizes, int n_in,
                              void* d_out, int out_size, void* d_ws, size_t ws_size,
                              hipStream_t stream) {
    const float* x      = (const float*)d_in[0];
    const float* ow1    = (const float*)d_in[1];
    const float* ob1    = (const float*)d_in[2];
    const float* w1     = (const float*)d_in[3];
    const float* b1     = (const float*)d_in[4];
    const float* ow2    = (const float*)d_in[5];
    const float* ob2    = (const float*)d_in[6];
    const float* w2     = (const float*)d_in[7];
    const float* b2     = (const float*)d_in[8];
    const float* ow3    = (const float*)d_in[9];
    const float* ob3    = (const float*)d_in[10];
    const float* w3     = (const float*)d_in[11];
    const float* b3     = (const float*)d_in[12];
    const float* defo_w = (const float*)d_in[13];
    const float* defo_b = (const float*)d_in[14];
    const float* c3d_w  = (const float*)d_in[15];
    const float* c3d_b  = (const float*)d_in[16];
    float* out = (float*)d_out;

    // workspace carve-up (all 16B-aligned):
    float* Xp    = (float*)d_ws;                  // 11,837,440 B
    float* h_a   = Xp + XP_ELEMS;                 // 8,388,608 B
    float* h_b   = h_a + 256 * NPOS;              // 8,388,608 B
    float* d_buf = h_b + 256 * NPOS;              // 3,538,944 B (108 x 8192)
    unsigned short* wt_off  = (unsigned short*)(d_buf + 108 * NPOS);  // 27*128*256 bf16 = 1,769,472 B
    unsigned short* wt_main = wt_off + 27 * 128 * 256;                // 27*256*256 bf16 = 3,538,944 B
    // total ~37.5 MB

    const dim3 blk(256);
    const int PAD_G = (XP_ELEMS + 255) / 256;     // 11560
    const int WTO_G = 27 * 128 * 256 / 256;       // 3456
    const int WTM_G = 27 * 256 * 256 / 256;       // 6912

    // ---- layer 1 (features = x) ----
    pad_kernel<<<PAD_G, blk, 0, stream>>>(x, Xp);
    wtrans_kernel<<<WTO_G, blk, 0, stream>>>(ow1, wt_off, 108, 128);
    gemm_kernel<true><<<dim3(128, 1), blk, 0, stream>>>(Xp, wt_off, nullptr, ob1, d_buf, 108, 128, 2);
    wtrans_kernel<<<WTM_G, blk, 0, stream>>>(w1, wt_main, 256, 256);
    gemm_kernel<false><<<dim3(128, 2), blk, 0, stream>>>(Xp, wt_main, d_buf, b1, h_a, 256, 256, 1);

    // ---- layer 2 (features = h1) ----
    pad_kernel<<<PAD_G, blk, 0, stream>>>(h_a, Xp);
    wtrans_kernel<<<WTO_G, blk, 0, stream>>>(ow2, wt_off, 108, 128);
    gemm_kernel<true><<<dim3(128, 1), blk, 0, stream>>>(Xp, wt_off, nullptr, ob2, d_buf, 108, 128, 2);
    wtrans_kernel<<<WTM_G, blk, 0, stream>>>(w2, wt_main, 256, 256);
    gemm_kernel<false><<<dim3(128, 2), blk, 0, stream>>>(Xp, wt_main, d_buf, b2, h_b, 256, 256, 1);

    // ---- layer 3 (features = h2) ----
    pad_kernel<<<PAD_G, blk, 0, stream>>>(h_b, Xp);
    wtrans_kernel<<<WTO_G, blk, 0, stream>>>(ow3, wt_off, 108, 128);
    gemm_kernel<true><<<dim3(128, 1), blk, 0, stream>>>(Xp, wt_off, nullptr, ob3, d_buf, 108, 128, 2);
    wtrans_kernel<<<WTM_G, blk, 0, stream>>>(w3, wt_main, 256, 256);
    gemm_kernel<false><<<dim3(128, 2), blk, 0, stream>>>(Xp, wt_main, d_buf, b3, h_a, 256, 256, 1);

    // ---- final: offset conv on h3, deformable conv samples ORIGINAL x, no relu ----
    pad_kernel<<<PAD_G, blk, 0, stream>>>(h_a, Xp);
    wtrans_kernel<<<WTO_G, blk, 0, stream>>>(defo_w, wt_off, 108, 128);
    gemm_kernel<true><<<dim3(128, 1), blk, 0, stream>>>(Xp, wt_off, nullptr, defo_b, d_buf, 108, 128, 2);
    pad_kernel<<<PAD_G, blk, 0, stream>>>(x, Xp);
    wtrans_kernel<<<WTM_G, blk, 0, stream>>>(c3d_w, wt_main, 256, 256);
    gemm_kernel<false><<<dim3(128, 2), blk, 0, stream>>>(Xp, wt_main, d_buf, c3d_b, out, 256, 256, 0);
}

// Round 2
// 1025.667 us; speedup vs baseline: 4.6979x; 4.6979x over previous
//
#include <hip/hip_runtime.h>
#include <cstdint>

// ---------------- problem constants ----------------
#define NPOS 8192              // 8*32*32 spatial positions
#define KTOT 6912              // 27 taps * 256 channels
#define XP_ROWS 11560          // 10*34*34 padded spatial rows
#define XP_SY 34
#define XP_SZ 1156             // 34*34

typedef float  facc_t __attribute__((ext_vector_type(4)));
typedef short  bf8_t  __attribute__((ext_vector_type(8)));   // 8 bf16 (4 VGPRs) MFMA frag
typedef unsigned short us4_t __attribute__((ext_vector_type(4)));

__device__ __forceinline__ unsigned short f2bf(float f) {
    unsigned u = __float_as_uint(f);
    u = (u + 0x7FFFu + ((u >> 16) & 1u)) >> 16;   // RNE
    return (unsigned short)u;
}
__device__ __forceinline__ float bf2f(unsigned short u) {
    return __uint_as_float(((unsigned)u) << 16);
}

// async global->LDS, 16B per lane, dest = wave-uniform base + lane*16
__device__ __forceinline__ void gl_lds16(const unsigned short* g, unsigned short* l) {
    __builtin_amdgcn_global_load_lds(
        (const __attribute__((address_space(1))) unsigned int*)g,
        (__attribute__((address_space(3))) unsigned int*)l, 16, 0, 0);
}

// ---------------- pad: fp32 c-major x (256,8192) -> pos-major bf16 Xp[row][256] ----------------
__global__ __launch_bounds__(256) void pad_x_kernel(const float* __restrict__ x,
                                                    unsigned short* __restrict__ Xp) {
    int row = blockIdx.x;            // 0..11559
    int c = threadIdx.x;
    int zp = row / XP_SZ;
    int r2 = row - zp * XP_SZ;
    int yp = r2 / XP_SY;
    int xp = r2 - yp * XP_SY;
    float v = 0.f;
    if (zp >= 1 && zp <= 8 && yp >= 1 && yp <= 32 && xp >= 1 && xp <= 32) {
        v = x[c * NPOS + ((zp - 1) << 10) + ((yp - 1) << 5) + (xp - 1)];
    }
    Xp[row * 256 + c] = f2bf(v);
}

// ---------------- pad: bf16 p-major h (8192,256) -> Xp[row][256] ----------------
__global__ __launch_bounds__(256) void pad_h_kernel(const unsigned short* __restrict__ h,
                                                    unsigned short* __restrict__ Xp) {
    int row = blockIdx.x;
    int c = threadIdx.x;
    int zp = row / XP_SZ;
    int r2 = row - zp * XP_SZ;
    int yp = r2 / XP_SY;
    int xp = r2 - yp * XP_SY;
    unsigned short v = 0;
    if (zp >= 1 && zp <= 8 && yp >= 1 && yp <= 32 && xp >= 1 && xp <= 32) {
        int p = ((zp - 1) << 10) + ((yp - 1) << 5) + (xp - 1);
        v = h[p * 256 + c];
    }
    Xp[row * 256 + c] = v;
}

// ---------------- weight transpose: (O,256,27) f32 -> [Opad][KTOT] bf16, kc = k*256+c ----------------
// grid = Opad*27 blocks x 256 thr
__global__ __launch_bounds__(256) void wtrans_kernel(const float* __restrict__ w,
                                                     unsigned short* __restrict__ wt,
                                                     int O) {
    int b = blockIdx.x;
    int o = b / 27;
    int k = b - o * 27;          // kc block base = k*256
    int c = threadIdx.x;
    float v = (o < O) ? w[(o * 256 + c) * 27 + k] : 0.f;
    wt[o * KTOT + k * 256 + c] = f2bf(v);
}

// ---------------- sampling: one wave per (p,k); 64 lanes x 4 ch = 256 channels ----------------
// S[p][k*256+c] = mask * trilinear(Xp, tap+offset)
__global__ __launch_bounds__(256) void samp_kernel(const unsigned short* __restrict__ Xp,
                                                   const float* __restrict__ dbuf,
                                                   unsigned short* __restrict__ S) {
    int wv = threadIdx.x >> 6;
    int lane = threadIdx.x & 63;
    int wid = blockIdx.x * 4 + wv;               // 0..221183
    int p = wid / 27;
    int k = wid - p * 27;
    int z = p >> 10, y = (p >> 5) & 31, x = p & 31;
    int kd = k / 9, kh = (k / 3) % 3, kw = k % 3;

    // wave-uniform offset/mask loads
    float od = dbuf[(3 * k + 0) * NPOS + p];
    float oh = dbuf[(3 * k + 1) * NPOS + p];
    float ow = dbuf[(3 * k + 2) * NPOS + p];
    float m  = dbuf[(81 + k) * NPOS + p];

    float cd = (float)(z + kd - 1) + od;
    float ch = (float)(y + kh - 1) + oh;
    float cx = (float)(x + kw - 1) + ow;
    float fdf = floorf(cd), fhf = floorf(ch), fwf = floorf(cx);
    float fd = cd - fdf, fh = ch - fhf, fw = cx - fwf;
    int id = (int)fdf, ih = (int)fhf, iw = (int)fwf;
    float wz0 = 1.f - fd, wz1 = fd;
    if (id < -1 || id > 7)  { wz0 = 0.f; wz1 = 0.f; id = 0; }
    float wy0 = 1.f - fh, wy1 = fh;
    if (ih < -1 || ih > 31) { wy0 = 0.f; wy1 = 0.f; ih = 0; }
    float wx0 = 1.f - fw, wx1 = fw;
    if (iw < -1 || iw > 31) { wx0 = 0.f; wx1 = 0.f; iw = 0; }
    wz0 *= m; wz1 *= m;
    float w00 = wz0 * wy0, w01 = wz0 * wy1, w10 = wz1 * wy0, w11 = wz1 * wy1;
    float cw[8];
    cw[0] = w00 * wx0; cw[1] = w00 * wx1;
    cw[2] = w01 * wx0; cw[3] = w01 * wx1;
    cw[4] = w10 * wx0; cw[5] = w10 * wx1;
    cw[6] = w11 * wx0; cw[7] = w11 * wx1;

    int rowIdx0 = (id + 1) * XP_SZ + (ih + 1) * XP_SY + (iw + 1);
    const unsigned short* base = Xp + rowIdx0 * 256 + lane * 4;
    const int offs[8] = {0, 1, XP_SY, XP_SY + 1, XP_SZ, XP_SZ + 1, XP_SZ + XP_SY, XP_SZ + XP_SY + 1};

    float a0 = 0.f, a1 = 0.f, a2 = 0.f, a3 = 0.f;
#pragma unroll
    for (int j = 0; j < 8; ++j) {
        us4_t v = *(const us4_t*)(base + offs[j] * 256);
        a0 += cw[j] * bf2f(v[0]);
        a1 += cw[j] * bf2f(v[1]);
        a2 += cw[j] * bf2f(v[2]);
        a3 += cw[j] * bf2f(v[3]);
    }
    us4_t pk = {f2bf(a0), f2bf(a1), f2bf(a2), f2bf(a3)};
    *(us4_t*)&S[(size_t)p * KTOT + k * 256 + lane * 4] = pk;
}

// ---------------- unified GEMM: out[o][p] = sum_kc A[o][kc] * B[p][kc] ----------------
// IS_CONV: B rows gathered from Xp with integer tap shift; else from S (p-major).
// PT = p-tile (B rows per block); o-tile fixed 64. BK = 64, MFMA 16x16x32 bf16.
// XOR-swizzled LDS (col^(row&7)) to spread b128 reads over all banks, staged via global_load_lds.
// mode: 0 = fp32 o-major + bias; 1 = bf16 p-major + bias + relu; 2 = fp32 o-major + bias + sigmoid(o>=81), guard o<O
template<int PT, bool IS_CONV>
__global__ __launch_bounds__(256)
void gemm_k(const unsigned short* __restrict__ bsrc,
            const unsigned short* __restrict__ wt2,    // [Opad][KTOT]
            const float* __restrict__ bias,
            float* __restrict__ outf,
            unsigned short* __restrict__ outh,
            int mode, int O) {
    constexpr int NITER = (PT + 64) * 8 / 256;         // staging iterations (16B slots)
    __shared__ unsigned short lds[(PT + 64) * 64] __attribute__((aligned(16)));

    const int t = threadIdx.x;
    const int wv = t >> 6, lane = t & 63;
    const int q = lane >> 4, r = lane & 15;
    const int pbase = blockIdx.x * PT;
    const int obase = blockIdx.y * 64;

    // per-iteration global base pointers (chunk-invariant part)
    const unsigned short* gb[NITER];
#pragma unroll
    for (int i = 0; i < NITER; ++i) {
        int id = i * 256 + t;
        int row = id >> 3;
        int col = (id & 7) ^ (row & 7);                // XOR swizzle
        if (i < PT / 32) {                             // B-tile iterations
            int p = pbase + row;
            if (IS_CONV) {
                int z = p >> 10, yy = (p >> 5) & 31, xx = p & 31;
                gb[i] = bsrc + (z * XP_SZ + yy * XP_SY + xx) * 256 + col * 8;
            } else {
                gb[i] = bsrc + (size_t)p * KTOT + col * 8;
            }
        } else {                                        // A-tile iterations
            int o = obase + (row - PT);
            gb[i] = wt2 + (size_t)o * KTOT + col * 8;
        }
    }

    // chunk-invariant LDS frag offsets (elements)
    int aoff[2], boff[2][PT / 16];
#pragma unroll
    for (int sl = 0; sl < 2; ++sl) {
        int arow = PT + wv * 16 + r;
        aoff[sl] = arow * 64 + (((sl * 4 + q) ^ (arow & 7)) * 8);
#pragma unroll
        for (int ip = 0; ip < PT / 16; ++ip) {
            int brow = ip * 16 + r;
            boff[sl][ip] = brow * 64 + (((sl * 4 + q) ^ (brow & 7)) * 8);
        }
    }

    facc_t acc[PT / 16];
#pragma unroll
    for (int ip = 0; ip < PT / 16; ++ip) acc[ip] = (facc_t){0.f, 0.f, 0.f, 0.f};

    for (int kc0 = 0; kc0 < KTOT; kc0 += 64) {
        int addB;
        if (IS_CONV) {
            int kU = kc0 >> 8;
            int kd = kU / 9, kh = (kU / 3) % 3, kw = kU % 3;
            addB = (kd * XP_SZ + kh * XP_SY + kw) * 256 + (kc0 & 255);
        } else {
            addB = kc0;
        }
#pragma unroll
        for (int i = 0; i < NITER; ++i) {
            const unsigned short* g = gb[i] + ((i < PT / 32) ? addB : kc0);
            gl_lds16(g, (unsigned short*)&lds[(i * 256 + (t & ~63)) * 8]);
        }
        __syncthreads();
#pragma unroll
        for (int sl = 0; sl < 2; ++sl) {
            bf8_t a = *(const bf8_t*)&lds[aoff[sl]];
#pragma unroll
            for (int ip = 0; ip < PT / 16; ++ip) {
                bf8_t b = *(const bf8_t*)&lds[boff[sl][ip]];
                acc[ip] = __builtin_amdgcn_mfma_f32_16x16x32_bf16(a, b, acc[ip], 0, 0, 0);
            }
        }
        __syncthreads();
    }

    // epilogue: C/D map row(o) = q*4+reg, col(p) = r  [verified R1]
    const int osub = obase + wv * 16 + q * 4;
#pragma unroll
    for (int ip = 0; ip < PT / 16; ++ip) {
        int p = pbase + ip * 16 + r;
        if (mode == 1) {
            us4_t pk;
#pragma unroll
            for (int reg = 0; reg < 4; ++reg) {
                float v = acc[ip][reg] + bias[osub + reg];
                pk[reg] = f2bf(fmaxf(v, 0.f));
            }
            *(us4_t*)&outh[p * 256 + osub] = pk;
        } else {
#pragma unroll
            for (int reg = 0; reg < 4; ++reg) {
                int o = osub + reg;
                if (o < O) {
                    float v = acc[ip][reg] + bias[o];
                    if (mode == 2 && o >= 81) v = 1.f / (1.f + __expf(-v));
                    outf[o * NPOS + p] = v;
                }
            }
        }
    }
}

// ---------------- host orchestration ----------------
extern "C" void kernel_launch(void* const* d_in, const int* in_sizes, int n_in,
                              void* d_out, int out_size, void* d_ws, size_t ws_size,
                              hipStream_t stream) {
    const float* x      = (const float*)d_in[0];
    const float* ow1    = (const float*)d_in[1];
    const float* ob1    = (const float*)d_in[2];
    const float* w1     = (const float*)d_in[3];
    const float* b1     = (const float*)d_in[4];
    const float* ow2    = (const float*)d_in[5];
    const float* ob2    = (const float*)d_in[6];
    const float* w2     = (const float*)d_in[7];
    const float* b2     = (const float*)d_in[8];
    const float* ow3    = (const float*)d_in[9];
    const float* ob3    = (const float*)d_in[10];
    const float* w3     = (const float*)d_in[11];
    const float* b3     = (const float*)d_in[12];
    const float* defo_w = (const float*)d_in[13];
    const float* defo_b = (const float*)d_in[14];
    const float* c3d_w  = (const float*)d_in[15];
    const float* c3d_b  = (const float*)d_in[16];
    float* out = (float*)d_out;

    // workspace carve-up (~132 MB)
    unsigned short* Xp     = (unsigned short*)d_ws;           // 11560*256       = 2,959,360 us
    unsigned short* S      = Xp + XP_ROWS * 256;              // 8192*6912       = 56,623,104 us
    unsigned short* h      = S + (size_t)NPOS * KTOT;         // 8192*256        = 2,097,152 us
    float*          dbuf   = (float*)(h + NPOS * 256);        // 108*8192 fp32   = 3,538,944 B
    unsigned short* wtoff  = (unsigned short*)(dbuf + 108 * NPOS);  // 128*6912  = 884,736 us
    unsigned short* wtmain = wtoff + 128 * KTOT;              // 256*6912        = 1,769,472 us

    const dim3 blk(256);
    const int SAMP_G = (NPOS * 27) / 4;     // 55296

    // ---- layer 1 (features = x) ----
    pad_x_kernel<<<XP_ROWS, blk, 0, stream>>>(x, Xp);
    wtrans_kernel<<<128 * 27, blk, 0, stream>>>(ow1, wtoff, 108);
    gemm_k<32, true><<<dim3(256, 2), blk, 0, stream>>>(Xp, wtoff, ob1, dbuf, nullptr, 2, 108);
    samp_kernel<<<SAMP_G, blk, 0, stream>>>(Xp, dbuf, S);
    wtrans_kernel<<<256 * 27, blk, 0, stream>>>(w1, wtmain, 256);
    gemm_k<64, false><<<dim3(128, 4), blk, 0, stream>>>(S, wtmain, b1, nullptr, h, 1, 256);

    // ---- layer 2 ----
    pad_h_kernel<<<XP_ROWS, blk, 0, stream>>>(h, Xp);
    wtrans_kernel<<<128 * 27, blk, 0, stream>>>(ow2, wtoff, 108);
    gemm_k<32, true><<<dim3(256, 2), blk, 0, stream>>>(Xp, wtoff, ob2, dbuf, nullptr, 2, 108);
    samp_kernel<<<SAMP_G, blk, 0, stream>>>(Xp, dbuf, S);
    wtrans_kernel<<<256 * 27, blk, 0, stream>>>(w2, wtmain, 256);
    gemm_k<64, false><<<dim3(128, 4), blk, 0, stream>>>(S, wtmain, b2, nullptr, h, 1, 256);

    // ---- layer 3 ----
    pad_h_kernel<<<XP_ROWS, blk, 0, stream>>>(h, Xp);
    wtrans_kernel<<<128 * 27, blk, 0, stream>>>(ow3, wtoff, 108);
    gemm_k<32, true><<<dim3(256, 2), blk, 0, stream>>>(Xp, wtoff, ob3, dbuf, nullptr, 2, 108);
    samp_kernel<<<SAMP_G, blk, 0, stream>>>(Xp, dbuf, S);
    wtrans_kernel<<<256 * 27, blk, 0, stream>>>(w3, wtmain, 256);
    gemm_k<64, false><<<dim3(128, 4), blk, 0, stream>>>(S, wtmain, b3, nullptr, h, 1, 256);

    // ---- final: offset conv on h3; deformable samples ORIGINAL x; no relu, fp32 o-major out ----
    pad_h_kernel<<<XP_ROWS, blk, 0, stream>>>(h, Xp);
    wtrans_kernel<<<128 * 27, blk, 0, stream>>>(defo_w, wtoff, 108);
    gemm_k<32, true><<<dim3(256, 2), blk, 0, stream>>>(Xp, wtoff, defo_b, dbuf, nullptr, 2, 108);
    pad_x_kernel<<<XP_ROWS, blk, 0, stream>>>(x, Xp);          // overwrite Xp with x (conv already done)
    samp_kernel<<<SAMP_G, blk, 0, stream>>>(Xp, dbuf, S);
    wtrans_kernel<<<256 * 27, blk, 0, stream>>>(c3d_w, wtmain, 256);
    gemm_k<64, false><<<dim3(128, 4), blk, 0, stream>>>(S, wtmain, c3d_b, out, nullptr, 0, 256);
}

// Round 3
// 766.144 us; speedup vs baseline: 6.2892x; 1.3387x over previous
//
#include <hip/hip_runtime.h>
#include <cstdint>

// ---------------- problem constants ----------------
#define NPOS 8192              // 8*32*32 spatial positions
#define KTOT 6912              // 27 taps * 256 channels
#define XP_ROWS 11560          // 10*34*34 padded spatial rows
#define XP_SY 34
#define XP_SZ 1156             // 34*34
#define KS 4                   // K-splits
#define KSL 1728               // KTOT/KS

typedef float  facc_t __attribute__((ext_vector_type(4)));
typedef short  bf8_t  __attribute__((ext_vector_type(8)));   // MFMA bf16 frag (4 VGPRs)
typedef unsigned short ub8_t __attribute__((ext_vector_type(8)));

__device__ __forceinline__ unsigned short f2bf(float f) {
    unsigned u = __float_as_uint(f);
    u = (u + 0x7FFFu + ((u >> 16) & 1u)) >> 16;   // RNE
    return (unsigned short)u;
}
__device__ __forceinline__ float bf2f(unsigned short u) {
    return __uint_as_float(((unsigned)u) << 16);
}

// ---------------- zero XpA+XpB (adjacent, 2*2,959,360 us) ----------------
__global__ __launch_bounds__(256) void zero_k(unsigned short* __restrict__ dst) {
    ub8_t zz = {0,0,0,0,0,0,0,0};
    *(ub8_t*)&dst[((size_t)blockIdx.x * 256 + threadIdx.x) * 8] = zz;
}

// ---------------- pad x: fp32 c-major (256,8192) -> interior of XpA[row][256] bf16 ----------------
// grid 256 = (z*32+y); LDS transpose so both sides are coalesced
__global__ __launch_bounds__(256) void pad_x_t(const float* __restrict__ x,
                                               unsigned short* __restrict__ XpA) {
    __shared__ unsigned short T[256 * 33];
    int b = blockIdx.x;
    int z = b >> 5, y = b & 31;
    int t = threadIdx.x;
    int c8 = t >> 5, xv = t & 31;
#pragma unroll 4
    for (int i = 0; i < 32; ++i) {
        int c = i * 8 + c8;
        T[c * 33 + xv] = f2bf(x[c * NPOS + (z << 10) + (y << 5) + xv]);
    }
    __syncthreads();
    int rowb = ((z + 1) * XP_SZ + (y + 1) * XP_SY + 1) * 256;
#pragma unroll 4
    for (int j = 0; j < 32; ++j) {
        XpA[rowb + j * 256 + t] = T[t * 33 + j];
    }
}

// ---------------- all 8 weight transposes in one launch ----------------
// src w[o][c][k] fp32 (row = 6912 contiguous) -> dst[o][k*256+c] bf16
__global__ __launch_bounds__(256) void wtrans_all(
    const float* __restrict__ o1, const float* __restrict__ o2,
    const float* __restrict__ o3, const float* __restrict__ o4,
    const float* __restrict__ m1, const float* __restrict__ m2,
    const float* __restrict__ m3, const float* __restrict__ m4,
    unsigned short* __restrict__ wtoff, unsigned short* __restrict__ wtmain) {
    __shared__ float T[6912];
    int b = blockIdx.x, t = threadIdx.x;
    const float* src; unsigned short* dst; int o, O;
    if (b < 512) {
        int L = b >> 7; o = b & 127; O = 108;
        src = (L == 0) ? o1 : (L == 1) ? o2 : (L == 2) ? o3 : o4;
        dst = wtoff + ((size_t)(L * 128 + o)) * KTOT;
    } else {
        int b2 = b - 512;
        int L = b2 >> 8; o = b2 & 255; O = 256;
        src = (L == 0) ? m1 : (L == 1) ? m2 : (L == 2) ? m3 : m4;
        dst = wtmain + ((size_t)(L * 256 + o)) * KTOT;
    }
    if (o < O) {
#pragma unroll 3
        for (int i = 0; i < 27; ++i) T[i * 256 + t] = src[(size_t)o * KTOT + i * 256 + t];
        __syncthreads();
#pragma unroll 3
        for (int i = 0; i < 27; ++i) {
            int kc = i * 256 + t;
            int c = kc & 255, k = kc >> 8;
            dst[kc] = f2bf(T[c * 27 + k]);
        }
    } else {
#pragma unroll 3
        for (int i = 0; i < 27; ++i) dst[i * 256 + t] = 0;
    }
}

// ---------------- fused implicit GEMM (conv or deformable), K-split partials ----------------
// parts[ks][O][8192] += A[o][kc]*B[p][kc] over kc in [ks*1728, +1728)
// DEFORM: B staged per chunk by on-the-fly trilinear sampling from Xp (bf16 pos-major, padded)
// CONV:   B staged by integer-tap row copy from Xp
template<bool DEFORM>
__global__ __launch_bounds__(256)
void fgemm(const unsigned short* __restrict__ Xp,
           const unsigned short* __restrict__ wt,   // [O][KTOT] bf16
           const float* __restrict__ dbuf,          // [108][8192] (DEFORM only)
           float* __restrict__ parts) {
    constexpr int O   = DEFORM ? 256 : 128;
    constexpr int PWN = DEFORM ? 4 : 2;             // p-frags per wave
    __shared__ unsigned short Bs[64 * 64] __attribute__((aligned(16)));

    const int t = threadIdx.x;
    const int wave = t >> 6, lane = t & 63;
    const int q = lane >> 4, r = lane & 15;
    const int pbase = blockIdx.x * 64;
    const int ks = blockIdx.y;
    const int kstart = ks * KSL;

    const int obw = DEFORM ? (wave * 64) : ((wave >> 1) * 64);
    const int pfb = DEFORM ? 0 : ((wave & 1) * 32);

    // staging coords: thread -> (p_local = t>>2, 16 channels at csub)
    const int pl = t >> 2;
    const int csub = (t & 3) * 16;
    const int p = pbase + pl;
    const int z = p >> 10, y = (p >> 5) & 31, xx = p & 31;
    const int g0 = (t & 3) * 2;
    const int wr0 = pl * 64 + ((g0 ^ (pl & 7)) << 3);
    const int wr1 = pl * 64 + (((g0 + 1) ^ (pl & 7)) << 3);

    facc_t acc[4][PWN];
#pragma unroll
    for (int i = 0; i < 4; ++i)
#pragma unroll
        for (int ip = 0; ip < PWN; ++ip) acc[i][ip] = (facc_t){0.f, 0.f, 0.f, 0.f};

    float cw[8];
    int row0 = 0;
    int kprev = -1;

    for (int chunk = 0; chunk < KSL / 64; ++chunk) {
        const int kc0 = kstart + chunk * 64;
        const int k = kc0 >> 8;
        const int c0 = kc0 & 255;
        const int kd = k / 9, kh = (k / 3) % 3, kw = k % 3;

        // ---- A-fragments straight from global (L2-resident weights) ----
        bf8_t afr[2][4];
#pragma unroll
        for (int sl = 0; sl < 2; ++sl)
#pragma unroll
            for (int i = 0; i < 4; ++i)
                afr[sl][i] = *(const bf8_t*)&wt[(size_t)(obw + i * 16 + r) * KTOT + kc0 + sl * 32 + q * 8];

        // ---- B staging ----
        if (DEFORM) {
            if (k != kprev) {
                kprev = k;
                float od  = dbuf[(3 * k + 0) * NPOS + p];
                float oh  = dbuf[(3 * k + 1) * NPOS + p];
                float ow_ = dbuf[(3 * k + 2) * NPOS + p];
                float m   = dbuf[(81 + k) * NPOS + p];
                float cd = (float)(z + kd - 1) + od;
                float ch = (float)(y + kh - 1) + oh;
                float cx = (float)(xx + kw - 1) + ow_;
                float fdf = floorf(cd), fhf = floorf(ch), fwf = floorf(cx);
                float fd = cd - fdf, fh = ch - fhf, fw = cx - fwf;
                float wz0 = 1.f - fd, wz1 = fd;
                float wy0 = 1.f - fh, wy1 = fh;
                float wx0 = 1.f - fw, wx1 = fw;
                int id, ih, iw;
                if (fdf < -1.f || fdf >= 8.f)  { wz0 = 0.f; wz1 = 0.f; id = 0; } else id = (int)fdf;
                if (fhf < -1.f || fhf >= 32.f) { wy0 = 0.f; wy1 = 0.f; ih = 0; } else ih = (int)fhf;
                if (fwf < -1.f || fwf >= 32.f) { wx0 = 0.f; wx1 = 0.f; iw = 0; } else iw = (int)fwf;
                wz0 *= m; wz1 *= m;
                float w00 = wz0 * wy0, w01 = wz0 * wy1, w10 = wz1 * wy0, w11 = wz1 * wy1;
                cw[0] = w00 * wx0; cw[1] = w00 * wx1;
                cw[2] = w01 * wx0; cw[3] = w01 * wx1;
                cw[4] = w10 * wx0; cw[5] = w10 * wx1;
                cw[6] = w11 * wx0; cw[7] = w11 * wx1;
                row0 = (id + 1) * XP_SZ + (ih + 1) * XP_SY + (iw + 1);
            }
            float av[16];
#pragma unroll
            for (int e = 0; e < 16; ++e) av[e] = 0.f;
            const unsigned short* cb = Xp + (size_t)row0 * 256 + c0 + csub;
#pragma unroll
            for (int j = 0; j < 8; ++j) {
                const int roff = ((j >> 2) & 1) * XP_SZ + ((j >> 1) & 1) * XP_SY + (j & 1);
                ub8_t lo = *(const ub8_t*)(cb + roff * 256);
                ub8_t hi = *(const ub8_t*)(cb + roff * 256 + 8);
#pragma unroll
                for (int e = 0; e < 8; ++e) {
                    av[e]     += cw[j] * bf2f(lo[e]);
                    av[8 + e] += cw[j] * bf2f(hi[e]);
                }
            }
            ub8_t v0, v1;
#pragma unroll
            for (int e = 0; e < 8; ++e) { v0[e] = f2bf(av[e]); v1[e] = f2bf(av[8 + e]); }
            *(ub8_t*)&Bs[wr0] = v0;
            *(ub8_t*)&Bs[wr1] = v1;
        } else {
            int row = (z + kd) * XP_SZ + (y + kh) * XP_SY + (xx + kw);
            ub8_t lo = *(const ub8_t*)&Xp[(size_t)row * 256 + c0 + csub];
            ub8_t hi = *(const ub8_t*)&Xp[(size_t)row * 256 + c0 + csub + 8];
            *(ub8_t*)&Bs[wr0] = lo;
            *(ub8_t*)&Bs[wr1] = hi;
        }
        __syncthreads();

        // ---- MFMA ----
#pragma unroll
        for (int sl = 0; sl < 2; ++sl) {
            bf8_t bfr[PWN];
#pragma unroll
            for (int ip = 0; ip < PWN; ++ip) {
                int brow = pfb + ip * 16 + r;
                bfr[ip] = *(const bf8_t*)&Bs[brow * 64 + (((sl * 4 + q) ^ (brow & 7)) << 3)];
            }
#pragma unroll
            for (int i = 0; i < 4; ++i)
#pragma unroll
                for (int ip = 0; ip < PWN; ++ip)
                    acc[i][ip] = __builtin_amdgcn_mfma_f32_16x16x32_bf16(afr[sl][i], bfr[ip], acc[i][ip], 0, 0, 0);
        }
        __syncthreads();
    }

    // ---- epilogue: fp32 partials; C/D map row(o)=q*4+reg, col(p)=r [R1/R2-verified] ----
    float* pp = parts + (size_t)ks * O * NPOS;
#pragma unroll
    for (int i = 0; i < 4; ++i)
#pragma unroll
        for (int ip = 0; ip < PWN; ++ip)
#pragma unroll
            for (int reg = 0; reg < 4; ++reg) {
                int o = obw + i * 16 + q * 4 + reg;
                int px = pbase + pfb + ip * 16 + r;
                pp[(size_t)o * NPOS + px] = acc[i][ip][reg];
            }
}

// ---------------- combine conv partials -> dbuf (bias + sigmoid on o>=81) ----------------
__global__ __launch_bounds__(256) void ccombine(const float* __restrict__ parts,
                                                const float* __restrict__ ob,
                                                float* __restrict__ dbuf) {
    int b = blockIdx.x;                 // 108*8
    int o = b >> 3;
    int p4 = ((b & 7) * 256 + threadIdx.x) * 4;
    float s0 = 0, s1 = 0, s2 = 0, s3 = 0;
#pragma unroll
    for (int s = 0; s < KS; ++s) {
        const float4 v = *(const float4*)&parts[((size_t)(s * 128 + o)) * NPOS + p4];
        s0 += v.x; s1 += v.y; s2 += v.z; s3 += v.w;
    }
    float bv = ob[o];
    s0 += bv; s1 += bv; s2 += bv; s3 += bv;
    if (o >= 81) {
        s0 = 1.f / (1.f + __expf(-s0));
        s1 = 1.f / (1.f + __expf(-s1));
        s2 = 1.f / (1.f + __expf(-s2));
        s3 = 1.f / (1.f + __expf(-s3));
    }
    *(float4*)&dbuf[(size_t)o * NPOS + p4] = make_float4(s0, s1, s2, s3);
}

// ---------------- combine deform partials -> relu bf16, transposed into XpB interior ----------------
// grid (128 p-tiles, 4 o-tiles)
__global__ __launch_bounds__(256) void dcombine_h(const float* __restrict__ parts,
                                                  const float* __restrict__ bias,
                                                  unsigned short* __restrict__ XpB) {
    __shared__ unsigned short T[64 * 66];
    int p0 = blockIdx.x * 64, o0 = blockIdx.y * 64;
    int t = threadIdx.x;
    int pl = t & 63, og = t >> 6;
#pragma unroll 4
    for (int j = 0; j < 16; ++j) {
        int ol = og * 16 + j;
        float s = 0.f;
#pragma unroll
        for (int sp = 0; sp < KS; ++sp)
            s += parts[((size_t)(sp * 256 + o0 + ol)) * NPOS + p0 + pl];
        s += bias[o0 + ol];
        T[ol * 66 + pl] = f2bf(fmaxf(s, 0.f));
    }
    __syncthreads();
    int c = t & 63, pr = t >> 6;
#pragma unroll 4
    for (int j = 0; j < 16; ++j) {
        int pl2 = j * 4 + pr;
        int pg = p0 + pl2;
        int zz = pg >> 10, yy = (pg >> 5) & 31, xv = pg & 31;
        int row = (zz + 1) * XP_SZ + (yy + 1) * XP_SY + xv + 1;
        XpB[(size_t)row * 256 + o0 + c] = T[c * 66 + pl2];
    }
}

// ---------------- final combine -> fp32 o-major output (bias only) ----------------
__global__ __launch_bounds__(256) void dcombine_out(const float* __restrict__ parts,
                                                    const float* __restrict__ bias,
                                                    float* __restrict__ out) {
    int b = blockIdx.x;                 // 256*8
    int o = b >> 3;
    int p4 = ((b & 7) * 256 + threadIdx.x) * 4;
    float s0 = 0, s1 = 0, s2 = 0, s3 = 0;
#pragma unroll
    for (int s = 0; s < KS; ++s) {
        const float4 v = *(const float4*)&parts[((size_t)(s * 256 + o)) * NPOS + p4];
        s0 += v.x; s1 += v.y; s2 += v.z; s3 += v.w;
    }
    float bv = bias[o];
    *(float4*)&out[(size_t)o * NPOS + p4] = make_float4(s0 + bv, s1 + bv, s2 + bv, s3 + bv);
}

// ---------------- host orchestration ----------------
extern "C" void kernel_launch(void* const* d_in, const int* in_sizes, int n_in,
                              void* d_out, int out_size, void* d_ws, size_t ws_size,
                              hipStream_t stream) {
    const float* x      = (const float*)d_in[0];
    const float* ow1    = (const float*)d_in[1];
    const float* ob1    = (const float*)d_in[2];
    const float* w1     = (const float*)d_in[3];
    const float* b1     = (const float*)d_in[4];
    const float* ow2    = (const float*)d_in[5];
    const float* ob2    = (const float*)d_in[6];
    const float* w2     = (const float*)d_in[7];
    const float* b2     = (const float*)d_in[8];
    const float* ow3    = (const float*)d_in[9];
    const float* ob3    = (const float*)d_in[10];
    const float* w3     = (const float*)d_in[11];
    const float* b3     = (const float*)d_in[12];
    const float* defo_w = (const float*)d_in[13];
    const float* defo_b = (const float*)d_in[14];
    const float* c3d_w  = (const float*)d_in[15];
    const float* c3d_b  = (const float*)d_in[16];
    float* out = (float*)d_out;

    // workspace carve-up (~70 MB)
    unsigned short* XpA    = (unsigned short*)d_ws;          // 2,959,360 us
    unsigned short* XpB    = XpA + (size_t)XP_ROWS * 256;    // 2,959,360 us (adjacent for zero_k)
    unsigned short* wtoff  = XpB + (size_t)XP_ROWS * 256;    // 4*128*6912
    unsigned short* wtmain = wtoff + (size_t)4 * 128 * KTOT; // 4*256*6912
    float* dbufp = (float*)(wtmain + (size_t)4 * 256 * KTOT);// 108*8192 fp32
    float* parts = dbufp + (size_t)108 * NPOS;               // 4*256*8192 fp32

    const dim3 blk(256);
    const dim3 gG(128, KS);

    zero_k<<<2890, blk, 0, stream>>>(XpA);                   // zeros XpA + XpB
    pad_x_t<<<256, blk, 0, stream>>>(x, XpA);
    wtrans_all<<<1536, blk, 0, stream>>>(ow1, ow2, ow3, defo_w, w1, w2, w3, c3d_w, wtoff, wtmain);

    const float* cbias[4] = {ob1, ob2, ob3, defo_b};
    const float* dbias[4] = {b1, b2, b3, c3d_b};

    for (int L = 0; L < 4; ++L) {
        const unsigned short* featConv = (L == 0) ? XpA : XpB;          // conv input = h_{L-1}
        const unsigned short* featDef  = (L == 3) ? XpA : featConv;     // final deform samples original x
        fgemm<false><<<gG, blk, 0, stream>>>(featConv, wtoff + (size_t)L * 128 * KTOT, nullptr, parts);
        ccombine<<<864, blk, 0, stream>>>(parts, cbias[L], dbufp);
        fgemm<true><<<gG, blk, 0, stream>>>(featDef, wtmain + (size_t)L * 256 * KTOT, dbufp, parts);
        if (L < 3) dcombine_h<<<dim3(128, 4), blk, 0, stream>>>(parts, dbias[L], XpB);
        else       dcombine_out<<<2048, blk, 0, stream>>>(parts, dbias[L], out);
    }
}